// Round 13
// baseline (331.473 us; speedup 1.0000x reference)
//
#include <hip/hip_runtime.h>
#include <hip/hip_bf16.h>
#include <stdint.h>

#define N_NODES 100000
#define N_EDGES 1600000
#define DIM 128
#define N_GRAPHS 128
#define LDA 136    // padded LDS stride in bf16 elems (MFMA phase)

#define NTILE 1563 // 64-node tiles: tile = dst >> 6
#define TCAP 1536  // per-tile colx capacity (mean padded ~1120, +12 sigma)

#define NBIN_BLK 391 // ceil(1.6M / 4096) binA blocks inside k_prep
#define CVT_BLK 3125 // 12.8M floats / (512*8)

typedef unsigned int uint32;
typedef unsigned short ushort16;

typedef __bf16 bf16x8 __attribute__((ext_vector_type(8)));
typedef float fx4 __attribute__((ext_vector_type(4)));

__device__ __forceinline__ float bfLo(uint32 u){ return __builtin_bit_cast(float, (uint32)(u << 16)); }
__device__ __forceinline__ float bfHi(uint32 u){ return __builtin_bit_cast(float, (uint32)(u & 0xFFFF0000u)); }
__device__ __forceinline__ ushort16 f2bf(float f){
  uint32 u = __builtin_bit_cast(uint32, f);
  u = u + 0x7FFFu + ((u >> 16) & 1u);   // round-to-nearest-even
  return (ushort16)(u >> 16);
}
__device__ __forceinline__ uint32 pack2(float a, float b){
  return (uint32)f2bf(a) | ((uint32)f2bf(b) << 16);
}

// ---------- fused prep: binA tile-binning (blocks 0..390) + x->bf16 cvt (391..3515)
//            + pad-row zero (3516) + frag-major W cvt (3517..3540) ----------
// binA: count per-tile in LDS hist, reserve runs via tileCursor atomics, then
// direct scatter writes into colx (no staging).
__global__ __launch_bounds__(512) void k_prep(const float* __restrict__ x,
                                              const float* __restrict__ W1, const float* __restrict__ W2,
                                              const int* __restrict__ ei,
                                              ushort16* __restrict__ P, ushort16* __restrict__ Q,
                                              ushort16* __restrict__ Wf,
                                              int* __restrict__ tileCursor,
                                              int* __restrict__ colx){
  __shared__ int hist[NTILE];
  __shared__ int gbase[NTILE];

  int bb = blockIdx.x;
  int t  = threadIdx.x;

  if (bb < NBIN_BLK){
    // ---- binA: bin 4096 edges into per-tile runs of colx ----
    int e0 = bb * 4096;
    for (int i = t; i < NTILE; i += 512) hist[i] = 0;
    __syncthreads();

    int   myv[8];
    short myb[8];
    short myr[8];
    #pragma unroll
    for (int it = 0; it < 8; ++it){
      int e = e0 + it*512 + t;
      int v = 0; short b = -1; short r = 0;
      if (e < N_EDGES){
        int s = ei[e];
        int d = ei[N_EDGES + e];
        b = (short)(d >> 6);              // tile id < 1563
        v = s | ((d & 63) << 17);         // src (17b) | local node (6b)
        r = (short)atomicAdd(&hist[b], 1);
      }
      myv[it] = v; myb[it] = b; myr[it] = r;
    }
    __syncthreads();

    for (int i = t; i < NTILE; i += 512){
      int h = hist[i];
      gbase[i] = h ? atomicAdd(&tileCursor[i], h) : 0;
    }
    __syncthreads();

    #pragma unroll
    for (int it = 0; it < 8; ++it){
      if (myb[it] >= 0){
        int g = gbase[myb[it]] + myr[it];
        if (g < TCAP) colx[myb[it]*TCAP + g] = myv[it];
      }
    }
    return;
  }

  if (bb < NBIN_BLK + CVT_BLK){
    // ---- cvt_x: 4096 floats per block ----
    int idx = ((bb - NBIN_BLK)*512 + t) * 8;
    float4 v0 = *(const float4*)(x + idx);
    float4 v1 = *(const float4*)(x + idx + 4);
    uint4 o;
    o.x = pack2(v0.x, v0.y); o.y = pack2(v0.z, v0.w);
    o.z = pack2(v1.x, v1.y); o.w = pack2(v1.z, v1.w);
    *(uint4*)(P + idx) = o;
    return;
  }

  if (bb == NBIN_BLK + CVT_BLK){
    // ---- zero the pad row (node N_NODES) in P and Q ----
    uint4 z = {0u,0u,0u,0u};
    if (t < 16)                *(uint4*)(P + (size_t)N_NODES*128 + t*8)      = z;
    else if (t < 32)           *(uint4*)(Q + (size_t)N_NODES*128 + (t-16)*8) = z;
    return;
  }

  // ---- cvt_w: frag-major Wf[(layer*2+mat)][nt][kt][lane][8] ----
  int tid = (bb - (NBIN_BLK + CVT_BLK + 1))*512 + t;   // 0..12287
  int layer = tid >> 12;
  int rem   = tid & 4095;
  int mat   = rem >> 11;
  int nt    = (rem >> 8) & 7;
  int kt    = (rem >> 6) & 3;
  int lane  = rem & 63;
  int kg = lane >> 4, m = lane & 15;
  int n  = nt*16 + m;
  int kb = kt*32 + kg*8;
  const float* src = (mat ? W2 : W1) + layer*16384;
  uint4 o;
  o.x = pack2(src[(kb+0)*128 + n], src[(kb+1)*128 + n]);
  o.y = pack2(src[(kb+2)*128 + n], src[(kb+3)*128 + n]);
  o.z = pack2(src[(kb+4)*128 + n], src[(kb+5)*128 + n]);
  o.w = pack2(src[(kb+6)*128 + n], src[(kb+7)*128 + n]);
  *(uint4*)(Wf + ((((size_t)(layer*2+mat)*8 + nt)*4 + kt)*64 + lane)*8) = o;
}

// ---------- fused GIN layer v10: champion body + degree-balanced gather perm ----------
// BUILD=true (layer 0): build tile CSR from unsorted colx run in LDS, write
// rowptr/rowlen + sorted colx back (binB-free). BUILD=false: stage sorted colx.
// NEW: nodes are processed in degree-RANK order -- q-step q handles ranks
// [16q,16q+16) across the 16 groups, so concurrent groups have near-equal len
// (no divergence waste) and all waves finish together (no barrier wait).
// Gather: 16-lane group per node, 8 independent row-gathers in flight.
// MLP: wave w owns cols [32w,32w+32), resident B-frags. LAST: pool epilogue.
template<bool BUILD, bool LAST>
__global__ __launch_bounds__(256, 6) void k_gin(const ushort16* __restrict__ xb, ushort16* __restrict__ hb,
                                                const ushort16* __restrict__ Wt1, const float* __restrict__ b1,
                                                const ushort16* __restrict__ Wt2, const float* __restrict__ b2,
                                                int* __restrict__ rowptr, int* __restrict__ rowlen,
                                                int* __restrict__ colx, const int* __restrict__ tileCursor,
                                                const int* __restrict__ batch, float* __restrict__ outp){
  __shared__ __attribute__((aligned(16))) ushort16 sA[64 * LDA];
  __shared__ __attribute__((aligned(16))) int sIdx[TCAP];
  __shared__ int sOff[64];
  __shared__ int sLen[64];
  __shared__ int sCur[64];
  __shared__ int sBat[64];
  __shared__ int sPerm[64];

  int t = threadIdx.x;
  int tb = blockIdx.x;
  int row0 = tb * 64;
  int jBase = tb * TCAP;

  if (BUILD){
    int* stage = (int*)sA;                       // sA dead until gather
    int cnt = min(tileCursor[tb], TCAP);
    if (t < 64) sLen[t] = 0;
    __syncthreads();
    for (int p = t; p < cnt; p += 256) stage[p] = colx[jBase + p];
    __syncthreads();
    for (int p = t; p < cnt; p += 256) atomicAdd(&sLen[stage[p] >> 17], 1);
    __syncthreads();

    int len = 0, plen = 0;
    if (t < 64){ len = sLen[t]; plen = (len + 3) & ~3; sCur[t] = plen; }
    __syncthreads();
    for (int off = 1; off < 64; off <<= 1){
      int x = 0;
      if (t < 64 && t >= off) x = sCur[t - off];
      __syncthreads();
      if (t < 64) sCur[t] += x;
      __syncthreads();
    }
    int excl = 0;
    if (t < 64){
      excl = sCur[t] - plen;
      sOff[t] = excl;
      sLen[t] = plen;
      int node = row0 + t;
      if (node < N_NODES){ rowptr[node] = jBase + excl; rowlen[node] = plen; }
      if (LAST) sBat[t] = (node < N_NODES) ? batch[node] : 0;
    }
    __syncthreads();
    if (t < 64){
      sCur[t] = excl;
      // degree rank (strict total order, ties by index): rank 0 = largest
      int L = sLen[t]; int r = 0;
      for (int j = 0; j < 64; ++j){
        int Lj = sLen[j];
        r += (Lj > L) || (Lj == L && j < t);
      }
      sPerm[r] = t;
    }
    __syncthreads();

    for (int p = t; p < cnt; p += 256){
      int v = stage[p];
      int d = v >> 17;
      int pos = atomicAdd(&sCur[d], 1);
      if (pos < TCAP) sIdx[pos] = v & 0x1FFFF;
    }
    __syncthreads();
    if (t < 64){
      for (int k = len; k < plen; ++k){
        int p = excl + k;
        if (p < TCAP) sIdx[p] = N_NODES;         // zero-row pad
      }
    }
    __syncthreads();

    int total = min(sOff[63] + sLen[63], TCAP);
    for (int p = t; p < total; p += 256) colx[jBase + p] = sIdx[p];  // sorted, for layers 1,2
  } else {
    if (t < 64){
      int gg = row0 + t;
      int off = 0, len = 0;
      if (gg < N_NODES){ off = rowptr[gg] - jBase; len = rowlen[gg]; }
      sOff[t] = off; sLen[t] = len;
      if (LAST) sBat[t] = (gg < N_NODES) ? batch[gg] : 0;
    }
    int lastV = min(row0 + 63, N_NODES - 1);
    int total = min(rowptr[lastV] + rowlen[lastV] - jBase, TCAP);
    for (int p = t; p < total; p += 256) sIdx[p] = colx[jBase + p];
    __syncthreads();
    if (t < 64){
      int L = sLen[t]; int r = 0;
      for (int j = 0; j < 64; ++j){
        int Lj = sLen[j];
        r += (Lj > L) || (Lj == L && j < t);
      }
      sPerm[r] = t;
    }
    __syncthreads();
  }

  int wave = t >> 6, lane = t & 63;
  int g16 = lane >> 4, o = lane & 15;
  const uint32* xw = (const uint32*)xb;

#define GATH(r) (*(const uint4*)(xw + (size_t)(r)*64 + o*4))
#define ACC8(u) do { \
    a0 += (fx4){ bfLo((u).x), bfHi((u).x), bfLo((u).y), bfHi((u).y) }; \
    a1 += (fx4){ bfLo((u).z), bfHi((u).z), bfLo((u).w), bfHi((u).w) }; \
  } while(0)

  for (int q = 0; q < 4; ++q){
    int ln  = sPerm[q*16 + wave*4 + g16];  // rank band q -> 16 near-equal lens
    int off = sOff[ln];
    int len = sLen[ln];                 // multiple of 4 (0 for pad nodes)
    int gn  = row0 + ln;
    uint4 xv = {0u,0u,0u,0u};
    if (gn < N_NODES) xv = *(const uint4*)(xw + (size_t)gn*64 + o*4);
    fx4 a0 = (fx4){0.f,0.f,0.f,0.f};
    fx4 a1 = (fx4){0.f,0.f,0.f,0.f};

    int rd = 0;
    for (; rd + 8 <= len; rd += 8){
      int i0 = sIdx[off+rd  ], i1 = sIdx[off+rd+1], i2 = sIdx[off+rd+2], i3 = sIdx[off+rd+3];
      int i4 = sIdx[off+rd+4], i5 = sIdx[off+rd+5], i6 = sIdx[off+rd+6], i7 = sIdx[off+rd+7];
      uint4 u0 = GATH(i0); uint4 u1 = GATH(i1); uint4 u2 = GATH(i2); uint4 u3 = GATH(i3);
      uint4 u4 = GATH(i4); uint4 u5 = GATH(i5); uint4 u6 = GATH(i6); uint4 u7 = GATH(i7);
      ACC8(u0); ACC8(u1); ACC8(u2); ACC8(u3);
      ACC8(u4); ACC8(u5); ACC8(u6); ACC8(u7);
    }
    if (rd < len){                      // exactly 4 remain
      int i0 = sIdx[off+rd], i1 = sIdx[off+rd+1], i2 = sIdx[off+rd+2], i3 = sIdx[off+rd+3];
      uint4 u0 = GATH(i0); uint4 u1 = GATH(i1); uint4 u2 = GATH(i2); uint4 u3 = GATH(i3);
      ACC8(u0); ACC8(u1); ACC8(u2); ACC8(u3);
    }

    uint4 r;
    r.x = pack2(a0[0]+bfLo(xv.x), a0[1]+bfHi(xv.x));
    r.y = pack2(a0[2]+bfLo(xv.y), a0[3]+bfHi(xv.y));
    r.z = pack2(a1[0]+bfLo(xv.z), a1[1]+bfHi(xv.z));
    r.w = pack2(a1[2]+bfLo(xv.w), a1[3]+bfHi(xv.w));
    *(uint4*)(sA + ln*LDA + o*8) = r;   // each lane writes its 16B of the node's row
  }
#undef GATH
#undef ACC8
  __syncthreads();                      // sA(x+agg) complete

  // ---- phase 2: MLP, wave w owns output cols [32w, 32w+32), resident B-frags ----
  int m = lane & 15, kg = lane >> 4;
  int n0 = wave * 2;                    // nt pair base

  bf16x8 bfa[4], bfb[4];
  #pragma unroll
  for (int kt = 0; kt < 4; ++kt){
    bfa[kt] = *(const bf16x8*)(Wt1 + (((n0+0)*4 + kt)*64 + lane)*8);
    bfb[kt] = *(const bf16x8*)(Wt1 + (((n0+1)*4 + kt)*64 + lane)*8);
  }

  fx4 acc[4][2];
  #pragma unroll
  for (int mt = 0; mt < 4; ++mt){ acc[mt][0] = (fx4){0,0,0,0}; acc[mt][1] = (fx4){0,0,0,0}; }

  #pragma unroll
  for (int kt = 0; kt < 4; ++kt){
    #pragma unroll
    for (int mt = 0; mt < 4; ++mt){
      bf16x8 av = *(const bf16x8*)(sA + (mt*16 + m)*LDA + kg*8 + kt*32);
      acc[mt][0] = __builtin_amdgcn_mfma_f32_16x16x32_bf16(av, bfa[kt], acc[mt][0], 0, 0, 0);
      acc[mt][1] = __builtin_amdgcn_mfma_f32_16x16x32_bf16(av, bfb[kt], acc[mt][1], 0, 0, 0);
    }
  }
  float bva = b1[(n0+0)*16 + m];
  float bvb = b1[(n0+1)*16 + m];
  __syncthreads();                      // all waves done reading sA(x+agg)

  #pragma unroll
  for (int mt = 0; mt < 4; ++mt){
    #pragma unroll
    for (int r = 0; r < 4; ++r){
      int row = mt*16 + kg*4 + r;
      sA[row*LDA + (n0+0)*16 + m] = f2bf(fmaxf(acc[mt][0][r] + bva, 0.f));
      sA[row*LDA + (n0+1)*16 + m] = f2bf(fmaxf(acc[mt][1][r] + bvb, 0.f));
    }
  }
  #pragma unroll
  for (int kt = 0; kt < 4; ++kt){
    bfa[kt] = *(const bf16x8*)(Wt2 + (((n0+0)*4 + kt)*64 + lane)*8);
    bfb[kt] = *(const bf16x8*)(Wt2 + (((n0+1)*4 + kt)*64 + lane)*8);
  }
  float cva = b2[(n0+0)*16 + m];
  float cvb = b2[(n0+1)*16 + m];
  #pragma unroll
  for (int mt = 0; mt < 4; ++mt){ acc[mt][0] = (fx4){0,0,0,0}; acc[mt][1] = (fx4){0,0,0,0}; }
  __syncthreads();                      // h fully written

  #pragma unroll
  for (int kt = 0; kt < 4; ++kt){
    #pragma unroll
    for (int mt = 0; mt < 4; ++mt){
      bf16x8 av = *(const bf16x8*)(sA + (mt*16 + m)*LDA + kg*8 + kt*32);
      acc[mt][0] = __builtin_amdgcn_mfma_f32_16x16x32_bf16(av, bfa[kt], acc[mt][0], 0, 0, 0);
      acc[mt][1] = __builtin_amdgcn_mfma_f32_16x16x32_bf16(av, bfb[kt], acc[mt][1], 0, 0, 0);
    }
  }

  if constexpr (!LAST){
    #pragma unroll
    for (int mt = 0; mt < 4; ++mt){
      #pragma unroll
      for (int r = 0; r < 4; ++r){
        int row = row0 + mt*16 + kg*4 + r;
        if (row < N_NODES){
          hb[row*128 + (n0+0)*16 + m] = f2bf(acc[mt][0][r] + cva);
          hb[row*128 + (n0+1)*16 + m] = f2bf(acc[mt][1][r] + cvb);
        }
      }
    }
  } else {
    // sum-pool epilogue: rows visited in increasing order per lane; batch sorted
    float sum0 = 0.f, sum1 = 0.f; int curg = -1;
    #pragma unroll
    for (int mt = 0; mt < 4; ++mt){
      #pragma unroll
      for (int r = 0; r < 4; ++r){
        int lrow = mt*16 + kg*4 + r;
        int grow = row0 + lrow;
        if (grow < N_NODES){
          int gg = sBat[lrow];
          if (gg != curg){
            if (curg >= 0){
              atomicAdd(&outp[curg*128 + (n0+0)*16 + m], sum0);
              atomicAdd(&outp[curg*128 + (n0+1)*16 + m], sum1);
            }
            curg = gg; sum0 = 0.f; sum1 = 0.f;
          }
          sum0 += acc[mt][0][r] + cva;
          sum1 += acc[mt][1][r] + cvb;
        }
      }
    }
    if (curg >= 0){
      atomicAdd(&outp[curg*128 + (n0+0)*16 + m], sum0);
      atomicAdd(&outp[curg*128 + (n0+1)*16 + m], sum1);
    }
  }
}

// ---------- launch ----------
extern "C" void kernel_launch(void* const* d_in, const int* in_sizes, int n_in,
                              void* d_out, int out_size, void* d_ws, size_t ws_size,
                              hipStream_t stream) {
  const float* x   = (const float*)d_in[0];
  const float* W1  = (const float*)d_in[1];
  const float* b1  = (const float*)d_in[2];
  const float* W2  = (const float*)d_in[3];
  const float* b2  = (const float*)d_in[4];
  const int*   ei  = (const int*)d_in[5];
  const int*   bat = (const int*)d_in[6];
  float* out = (float*)d_out;

  char* w = (char*)d_ws;
  auto carve = [&](size_t bytes) -> char* {
    char* p = w; w += (bytes + 255) & ~(size_t)255; return p;
  };
  ushort16* P    = (ushort16*)carve((size_t)(N_NODES+1) * DIM * 2);  // +1: zero pad row
  ushort16* Q    = (ushort16*)carve((size_t)(N_NODES+1) * DIM * 2);
  ushort16* Wf   = (ushort16*)carve((size_t)3 * 2 * 16384 * 2);      // frag-major weights
  int* rowptr    = (int*)carve((size_t)N_NODES * 4);
  int* rowlen    = (int*)carve((size_t)N_NODES * 4);
  int* colx      = (int*)carve((size_t)NTILE * TCAP * 4);   // 9.6 MB, fixed per-tile regions
  int* tileCursor = (int*)carve((NTILE + 1) * 4);

  hipMemsetAsync(tileCursor, 0, (NTILE + 1) * 4, stream);
  hipMemsetAsync(d_out, 0, (size_t)N_GRAPHS * DIM * 4, stream);

  // fused prep: binA (391) + cvt_x (3125) + pad-zero (1) + cvt_w (24)
  k_prep<<<NBIN_BLK + CVT_BLK + 1 + 24, 512, 0, stream>>>(x, W1, W2, ei, P, Q, Wf,
                                                          tileCursor, colx);

  const int ginGrid = NTILE;  // 1563

  // layer 0 builds tile CSRs in-kernel (binB eliminated); layers 1,2 reuse sorted colx
  k_gin<true,  false><<<ginGrid, 256, 0, stream>>>(P, Q, Wf + 0*16384, b1 + 0*128, Wf + 1*16384, b2 + 0*128,
                                                   rowptr, rowlen, colx, tileCursor, bat, out);
  k_gin<false, false><<<ginGrid, 256, 0, stream>>>(Q, P, Wf + 2*16384, b1 + 1*128, Wf + 3*16384, b2 + 1*128,
                                                   rowptr, rowlen, colx, tileCursor, bat, out);
  k_gin<false, true ><<<ginGrid, 256, 0, stream>>>(P, Q, Wf + 4*16384, b1 + 2*128, Wf + 5*16384, b2 + 2*128,
                                                   rowptr, rowlen, colx, tileCursor, bat, out);
}

// Round 14
// 325.481 us; speedup vs baseline: 1.0184x; 1.0184x over previous
//
#include <hip/hip_runtime.h>
#include <hip/hip_bf16.h>
#include <stdint.h>

#define N_NODES 100000
#define N_EDGES 1600000
#define DIM 128
#define N_GRAPHS 128
#define LDA 136   // padded LDS stride in bf16 elems (MFMA phase)

#define NBKT 392     // buckets of 256 nodes: bucket = dst >> 8
#define BCAP 6144    // per-bucket temp capacity (mean 4096, sigma ~64, +32 sigma)
#define BP   5632    // per-bucket padded colx capacity (mult of 4)
#define IDXCAP 2048  // per-64-node-tile staged colx slots (mean ~1120, +28 sigma)

#define NBIN_BLK 391 // ceil(1.6M / 4096) binA blocks inside k_prep
#define CVT_BLK 3125 // 12.8M floats / (512*8)

typedef unsigned int uint32;
typedef unsigned short ushort16;

typedef __bf16 bf16x8 __attribute__((ext_vector_type(8)));
typedef float fx4 __attribute__((ext_vector_type(4)));

__device__ __forceinline__ float bfLo(uint32 u){ return __builtin_bit_cast(float, (uint32)(u << 16)); }
__device__ __forceinline__ float bfHi(uint32 u){ return __builtin_bit_cast(float, (uint32)(u & 0xFFFF0000u)); }
__device__ __forceinline__ ushort16 f2bf(float f){
  uint32 u = __builtin_bit_cast(uint32, f);
  u = u + 0x7FFFu + ((u >> 16) & 1u);   // round-to-nearest-even
  return (ushort16)(u >> 16);
}
__device__ __forceinline__ uint32 pack2(float a, float b){
  return (uint32)f2bf(a) | ((uint32)f2bf(b) << 16);
}

// ---------- fused prep: binA histogram-sort (blocks 0..390) + x->bf16 cvt (391..3515)
//            + pad-row zero (3516) + frag-major W cvt (3517..3540) ----------
__global__ __launch_bounds__(512) void k_prep(const float* __restrict__ x,
                                              const float* __restrict__ W1, const float* __restrict__ W2,
                                              const int* __restrict__ ei,
                                              ushort16* __restrict__ P, ushort16* __restrict__ Q,
                                              ushort16* __restrict__ Wf,
                                              int* __restrict__ bucketCursor,
                                              int* __restrict__ temp){
  __shared__ int hist[NBKT];
  __shared__ int base[NBKT];
  __shared__ int gbase[NBKT];
  __shared__ int scanbuf[512];
  __shared__ int sVal[4096];
  __shared__ unsigned short sBkt[4096];

  int bb = blockIdx.x;
  int t  = threadIdx.x;

  if (bb < NBIN_BLK){
    // ---- binA: bin 4096 edges into per-bucket runs of temp ----
    int e0 = bb * 4096;
    for (int i = t; i < NBKT; i += 512) hist[i] = 0;
    __syncthreads();

    int   myv[8];
    short myb[8];
    short myr[8];
    #pragma unroll
    for (int it = 0; it < 8; ++it){
      int e = e0 + it*512 + t;
      int v = 0; short b = -1; short r = 0;
      if (e < N_EDGES){
        int s = ei[e];
        int d = ei[N_EDGES + e];
        b = (short)(d >> 8);
        v = s | ((d & 255) << 17);
        r = (short)atomicAdd(&hist[b], 1);
      }
      myv[it] = v; myb[it] = b; myr[it] = r;
    }
    __syncthreads();

    scanbuf[t] = (t < NBKT) ? hist[t] : 0;
    __syncthreads();
    for (int off = 1; off < 512; off <<= 1){
      int x2 = 0;
      if (t >= off) x2 = scanbuf[t - off];
      __syncthreads();
      scanbuf[t] += x2;
      __syncthreads();
    }
    if (t < NBKT){
      base[t]  = scanbuf[t] - hist[t];                 // exclusive
      gbase[t] = atomicAdd(&bucketCursor[t], hist[t]); // reserve run
    }
    __syncthreads();

    #pragma unroll
    for (int it = 0; it < 8; ++it){
      if (myb[it] >= 0){
        int p = base[myb[it]] + myr[it];
        sVal[p] = myv[it];
        sBkt[p] = (unsigned short)myb[it];
      }
    }
    __syncthreads();

    int cnt = scanbuf[NBKT - 1];
    for (int p = t; p < cnt; p += 512){
      int b = sBkt[p];
      int g = gbase[b] + (p - base[b]);
      if (g < BCAP) temp[b*BCAP + g] = sVal[p];
    }
    return;
  }

  if (bb < NBIN_BLK + CVT_BLK){
    // ---- cvt_x: 4096 floats per block ----
    int idx = ((bb - NBIN_BLK)*512 + t) * 8;
    float4 v0 = *(const float4*)(x + idx);
    float4 v1 = *(const float4*)(x + idx + 4);
    uint4 o;
    o.x = pack2(v0.x, v0.y); o.y = pack2(v0.z, v0.w);
    o.z = pack2(v1.x, v1.y); o.w = pack2(v1.z, v1.w);
    *(uint4*)(P + idx) = o;
    return;
  }

  if (bb == NBIN_BLK + CVT_BLK){
    // ---- zero the pad row (node N_NODES) in P and Q ----
    uint4 z = {0u,0u,0u,0u};
    if (t < 16)                *(uint4*)(P + (size_t)N_NODES*128 + t*8)      = z;
    else if (t < 32)           *(uint4*)(Q + (size_t)N_NODES*128 + (t-16)*8) = z;
    return;
  }

  // ---- cvt_w: frag-major Wf[(layer*2+mat)][nt][kt][lane][8] ----
  int tid = (bb - (NBIN_BLK + CVT_BLK + 1))*512 + t;   // 0..12287
  int layer = tid >> 12;
  int rem   = tid & 4095;
  int mat   = rem >> 11;
  int nt    = (rem >> 8) & 7;
  int kt    = (rem >> 6) & 3;
  int lane  = rem & 63;
  int kg = lane >> 4, m = lane & 15;
  int n  = nt*16 + m;
  int kb = kt*32 + kg*8;
  const float* src = (mat ? W2 : W1) + layer*16384;
  uint4 o;
  o.x = pack2(src[(kb+0)*128 + n], src[(kb+1)*128 + n]);
  o.y = pack2(src[(kb+2)*128 + n], src[(kb+3)*128 + n]);
  o.z = pack2(src[(kb+4)*128 + n], src[(kb+5)*128 + n]);
  o.w = pack2(src[(kb+6)*128 + n], src[(kb+7)*128 + n]);
  *(uint4*)(Wf + ((((size_t)(layer*2+mat)*8 + nt)*4 + kt)*64 + lane)*8) = o;
}

// ---------- binB: one block per 256-node bucket; build sub-CSR in LDS with per-node
// padding to multiple-of-4 (pad slots -> zero row N_NODES); coalesced colx write. ----------
__global__ __launch_bounds__(512) void k_binB(const int* __restrict__ temp,
                                              const int* __restrict__ bucketCursor,
                                              int* __restrict__ rowptr,
                                              int* __restrict__ rowlen,
                                              int* __restrict__ colx){
  __shared__ int counts[256];
  __shared__ int sc[256];
  __shared__ int cur[256];
  __shared__ int stage[BCAP];
  __shared__ int sorted[BCAP];
  int b = blockIdx.x, t = threadIdx.x;
  int cnt = min(bucketCursor[b], BCAP);
  int gb  = b * BP;
  const int* src = temp + b*BCAP;

  if (t < 256) counts[t] = 0;
  __syncthreads();
  for (int p = t; p < cnt; p += 512){
    int v = src[p];
    stage[p] = v;
    atomicAdd(&counts[v >> 17], 1);
  }
  __syncthreads();

  int len = 0, plen = 0;
  if (t < 256){
    len  = counts[t];
    plen = (len + 3) & ~3;          // padded to multiple of 4
    sc[t] = plen;
  }
  __syncthreads();
  for (int off = 1; off < 256; off <<= 1){
    int x = 0;
    if (t < 256 && t >= off) x = sc[t - off];
    __syncthreads();
    if (t < 256) sc[t] += x;
    __syncthreads();
  }
  int excl = 0;
  if (t < 256){
    excl = sc[t] - plen;
    cur[t] = excl;
    int node = b*256 + t;
    if (node < N_NODES){ rowptr[node] = gb + excl; rowlen[node] = plen; }
  }
  __syncthreads();

  for (int p = t; p < cnt; p += 512){
    int v = stage[p];
    int d = v >> 17;
    int pos = atomicAdd(&cur[d], 1);
    sorted[pos] = v & 0x1FFFF;
  }
  __syncthreads();

  // pad fill: each thread pads its own node (<=3 slots) with the zero row
  if (t < 256){
    for (int k = len; k < plen; ++k) sorted[excl + k] = N_NODES;
  }
  __syncthreads();

  int total = min(sc[255], BP);
  for (int p = t; p < total; p += 512) colx[gb + p] = sorted[p];
}

// ---------- fused GIN layer v8: R3-champion body (69us) + pool fusion ----------
// Phase 1: stage tile colx into sIdx LDS (coalesced, once); 16-lane group per
// node, 8 independent row-gathers in flight, indices from LDS. Phase 2: wave w
// owns output cols [32w,32w+32); resident B-frags (32 VGPR) from frag-major Wf.
// LDS 26.4 KB => 6 blocks/CU; (256,6); measured 40 VGPR.
// LAST=true: per-graph fp32 atomicAdd pool epilogue instead of hb write.
template<bool LAST>
__global__ __launch_bounds__(256, 6) void k_gin(const ushort16* __restrict__ xb, ushort16* __restrict__ hb,
                                                const ushort16* __restrict__ Wt1, const float* __restrict__ b1,
                                                const ushort16* __restrict__ Wt2, const float* __restrict__ b2,
                                                const int* __restrict__ rowptr, const int* __restrict__ rowlen,
                                                const int* __restrict__ colx,
                                                const int* __restrict__ batch, float* __restrict__ outp){
  __shared__ __attribute__((aligned(16))) ushort16 sA[64 * LDA];
  __shared__ __attribute__((aligned(16))) int sIdx[IDXCAP];
  __shared__ int sOff[64];
  __shared__ int sLen[64];
  __shared__ int sBat[64];

  int t = threadIdx.x;
  int row0 = blockIdx.x * 64;
  int jBase = rowptr[row0];
  int lastV = min(row0 + 63, N_NODES - 1);
  int total = rowptr[lastV] + rowlen[lastV] - jBase;

  if (t < 64){
    int gg = row0 + t;
    int off = 0, len = 0;
    if (gg < N_NODES){ off = rowptr[gg] - jBase; len = rowlen[gg]; }
    sOff[t] = off; sLen[t] = len;
    if (LAST) sBat[t] = (gg < N_NODES) ? batch[gg] : 0;
  }
  bool fast = (total <= IDXCAP);                 // block-uniform
  if (fast){
    for (int p = t; p < total; p += 256) sIdx[p] = colx[jBase + p];
  }
  __syncthreads();

  int wave = t >> 6, lane = t & 63;
  int g16 = lane >> 4, o = lane & 15;
  const uint32* xw = (const uint32*)xb;

#define GATH(r) (*(const uint4*)(xw + (size_t)(r)*64 + o*4))
#define ACC8(u) do { \
    a0 += (fx4){ bfLo((u).x), bfHi((u).x), bfLo((u).y), bfHi((u).y) }; \
    a1 += (fx4){ bfLo((u).z), bfHi((u).z), bfLo((u).w), bfHi((u).w) }; \
  } while(0)

  for (int q = 0; q < 4; ++q){
    int ln  = wave*16 + q*4 + g16;      // local node 0..63 (group-owned)
    int off = sOff[ln];
    int len = sLen[ln];                 // multiple of 4 (0 for pad nodes)
    int gn  = row0 + ln;
    uint4 xv = {0u,0u,0u,0u};
    if (gn < N_NODES) xv = *(const uint4*)(xw + (size_t)gn*64 + o*4);
    fx4 a0 = (fx4){0.f,0.f,0.f,0.f};
    fx4 a1 = (fx4){0.f,0.f,0.f,0.f};

    if (fast){
      int rd = 0;
      for (; rd + 8 <= len; rd += 8){
        int i0 = sIdx[off+rd  ], i1 = sIdx[off+rd+1], i2 = sIdx[off+rd+2], i3 = sIdx[off+rd+3];
        int i4 = sIdx[off+rd+4], i5 = sIdx[off+rd+5], i6 = sIdx[off+rd+6], i7 = sIdx[off+rd+7];
        uint4 u0 = GATH(i0); uint4 u1 = GATH(i1); uint4 u2 = GATH(i2); uint4 u3 = GATH(i3);
        uint4 u4 = GATH(i4); uint4 u5 = GATH(i5); uint4 u6 = GATH(i6); uint4 u7 = GATH(i7);
        ACC8(u0); ACC8(u1); ACC8(u2); ACC8(u3);
        ACC8(u4); ACC8(u5); ACC8(u6); ACC8(u7);
      }
      if (rd < len){                    // exactly 4 remain
        int i0 = sIdx[off+rd], i1 = sIdx[off+rd+1], i2 = sIdx[off+rd+2], i3 = sIdx[off+rd+3];
        uint4 u0 = GATH(i0); uint4 u1 = GATH(i1); uint4 u2 = GATH(i2); uint4 u3 = GATH(i3);
        ACC8(u0); ACC8(u1); ACC8(u2); ACC8(u3);
      }
    } else {                            // ~never: tile overflowed IDXCAP
      for (int rd = 0; rd < len; rd += 4){
        int i0 = colx[jBase+off+rd], i1 = colx[jBase+off+rd+1];
        int i2 = colx[jBase+off+rd+2], i3 = colx[jBase+off+rd+3];
        uint4 u0 = GATH(i0); uint4 u1 = GATH(i1); uint4 u2 = GATH(i2); uint4 u3 = GATH(i3);
        ACC8(u0); ACC8(u1); ACC8(u2); ACC8(u3);
      }
    }

    uint4 r;
    r.x = pack2(a0[0]+bfLo(xv.x), a0[1]+bfHi(xv.x));
    r.y = pack2(a0[2]+bfLo(xv.y), a0[3]+bfHi(xv.y));
    r.z = pack2(a1[0]+bfLo(xv.z), a1[1]+bfHi(xv.z));
    r.w = pack2(a1[2]+bfLo(xv.w), a1[3]+bfHi(xv.w));
    *(uint4*)(sA + ln*LDA + o*8) = r;   // each lane writes its 16B of the group's row
  }
#undef GATH
#undef ACC8
  __syncthreads();                      // sA(x+agg) complete

  // ---- phase 2: MLP, wave w owns output cols [32w, 32w+32), resident B-frags ----
  int m = lane & 15, kg = lane >> 4;
  int n0 = wave * 2;                    // nt pair base

  bf16x8 bfa[4], bfb[4];
  #pragma unroll
  for (int kt = 0; kt < 4; ++kt){
    bfa[kt] = *(const bf16x8*)(Wt1 + (((n0+0)*4 + kt)*64 + lane)*8);
    bfb[kt] = *(const bf16x8*)(Wt1 + (((n0+1)*4 + kt)*64 + lane)*8);
  }

  fx4 acc[4][2];
  #pragma unroll
  for (int mt = 0; mt < 4; ++mt){ acc[mt][0] = (fx4){0,0,0,0}; acc[mt][1] = (fx4){0,0,0,0}; }

  #pragma unroll
  for (int kt = 0; kt < 4; ++kt){
    #pragma unroll
    for (int mt = 0; mt < 4; ++mt){
      bf16x8 av = *(const bf16x8*)(sA + (mt*16 + m)*LDA + kg*8 + kt*32);
      acc[mt][0] = __builtin_amdgcn_mfma_f32_16x16x32_bf16(av, bfa[kt], acc[mt][0], 0, 0, 0);
      acc[mt][1] = __builtin_amdgcn_mfma_f32_16x16x32_bf16(av, bfb[kt], acc[mt][1], 0, 0, 0);
    }
  }
  float bva = b1[(n0+0)*16 + m];
  float bvb = b1[(n0+1)*16 + m];
  __syncthreads();                      // all waves done reading sA(x+agg)

  #pragma unroll
  for (int mt = 0; mt < 4; ++mt){
    #pragma unroll
    for (int r = 0; r < 4; ++r){
      int row = mt*16 + kg*4 + r;
      sA[row*LDA + (n0+0)*16 + m] = f2bf(fmaxf(acc[mt][0][r] + bva, 0.f));
      sA[row*LDA + (n0+1)*16 + m] = f2bf(fmaxf(acc[mt][1][r] + bvb, 0.f));
    }
  }
  #pragma unroll
  for (int kt = 0; kt < 4; ++kt){
    bfa[kt] = *(const bf16x8*)(Wt2 + (((n0+0)*4 + kt)*64 + lane)*8);
    bfb[kt] = *(const bf16x8*)(Wt2 + (((n0+1)*4 + kt)*64 + lane)*8);
  }
  float cva = b2[(n0+0)*16 + m];
  float cvb = b2[(n0+1)*16 + m];
  #pragma unroll
  for (int mt = 0; mt < 4; ++mt){ acc[mt][0] = (fx4){0,0,0,0}; acc[mt][1] = (fx4){0,0,0,0}; }
  __syncthreads();                      // h fully written

  #pragma unroll
  for (int kt = 0; kt < 4; ++kt){
    #pragma unroll
    for (int mt = 0; mt < 4; ++mt){
      bf16x8 av = *(const bf16x8*)(sA + (mt*16 + m)*LDA + kg*8 + kt*32);
      acc[mt][0] = __builtin_amdgcn_mfma_f32_16x16x32_bf16(av, bfa[kt], acc[mt][0], 0, 0, 0);
      acc[mt][1] = __builtin_amdgcn_mfma_f32_16x16x32_bf16(av, bfb[kt], acc[mt][1], 0, 0, 0);
    }
  }

  if constexpr (!LAST){
    #pragma unroll
    for (int mt = 0; mt < 4; ++mt){
      #pragma unroll
      for (int r = 0; r < 4; ++r){
        int row = row0 + mt*16 + kg*4 + r;
        if (row < N_NODES){
          hb[row*128 + (n0+0)*16 + m] = f2bf(acc[mt][0][r] + cva);
          hb[row*128 + (n0+1)*16 + m] = f2bf(acc[mt][1][r] + cvb);
        }
      }
    }
  } else {
    // sum-pool epilogue: rows visited in increasing order per lane; batch sorted
    float sum0 = 0.f, sum1 = 0.f; int curg = -1;
    #pragma unroll
    for (int mt = 0; mt < 4; ++mt){
      #pragma unroll
      for (int r = 0; r < 4; ++r){
        int lrow = mt*16 + kg*4 + r;
        int grow = row0 + lrow;
        if (grow < N_NODES){
          int gg = sBat[lrow];
          if (gg != curg){
            if (curg >= 0){
              atomicAdd(&outp[curg*128 + (n0+0)*16 + m], sum0);
              atomicAdd(&outp[curg*128 + (n0+1)*16 + m], sum1);
            }
            curg = gg; sum0 = 0.f; sum1 = 0.f;
          }
          sum0 += acc[mt][0][r] + cva;
          sum1 += acc[mt][1][r] + cvb;
        }
      }
    }
    if (curg >= 0){
      atomicAdd(&outp[curg*128 + (n0+0)*16 + m], sum0);
      atomicAdd(&outp[curg*128 + (n0+1)*16 + m], sum1);
    }
  }
}

// ---------- launch ----------
extern "C" void kernel_launch(void* const* d_in, const int* in_sizes, int n_in,
                              void* d_out, int out_size, void* d_ws, size_t ws_size,
                              hipStream_t stream) {
  const float* x   = (const float*)d_in[0];
  const float* W1  = (const float*)d_in[1];
  const float* b1  = (const float*)d_in[2];
  const float* W2  = (const float*)d_in[3];
  const float* b2  = (const float*)d_in[4];
  const int*   ei  = (const int*)d_in[5];
  const int*   bat = (const int*)d_in[6];
  float* out = (float*)d_out;

  char* w = (char*)d_ws;
  auto carve = [&](size_t bytes) -> char* {
    char* p = w; w += (bytes + 255) & ~(size_t)255; return p;
  };
  ushort16* P    = (ushort16*)carve((size_t)(N_NODES+1) * DIM * 2);  // +1: zero pad row
  ushort16* Q    = (ushort16*)carve((size_t)(N_NODES+1) * DIM * 2);
  ushort16* Wf   = (ushort16*)carve((size_t)3 * 2 * 16384 * 2);      // frag-major weights
  int* rowptr    = (int*)carve((size_t)N_NODES * 4);
  int* rowlen    = (int*)carve((size_t)N_NODES * 4);
  int* colx      = (int*)carve((size_t)NBKT * BP * 4);   // 8.83 MB, fixed bucket regions
  int* bucketCursor = (int*)carve((NBKT + 1) * 4);
  // temp bucket regions alias Q: only live during prep/binB, before any k_gin writes Q
  int* temp      = (int*)Q;

  hipMemsetAsync(bucketCursor, 0, (NBKT + 1) * 4, stream);
  hipMemsetAsync(d_out, 0, (size_t)N_GRAPHS * DIM * 4, stream);

  // fused prep: binA (391) + cvt_x (3125) + pad-zero (1) + cvt_w (24)
  k_prep<<<NBIN_BLK + CVT_BLK + 1 + 24, 512, 0, stream>>>(x, W1, W2, ei, P, Q, Wf,
                                                          bucketCursor, temp);
  k_binB<<<NBKT, 512, 0, stream>>>(temp, bucketCursor, rowptr, rowlen, colx);

  const int ginGrid = (N_NODES + 63) / 64;  // 1563

  // layer l: W1-frags at Wf + (l*2+0)*16384, W2-frags at Wf + (l*2+1)*16384
  k_gin<false><<<ginGrid, 256, 0, stream>>>(P, Q, Wf + 0*16384, b1 + 0*128, Wf + 1*16384, b2 + 0*128,
                                            rowptr, rowlen, colx, bat, out);
  k_gin<false><<<ginGrid, 256, 0, stream>>>(Q, P, Wf + 2*16384, b1 + 1*128, Wf + 3*16384, b2 + 1*128,
                                            rowptr, rowlen, colx, bat, out);
  k_gin<true><<<ginGrid, 256, 0, stream>>>(P, Q, Wf + 4*16384, b1 + 2*128, Wf + 5*16384, b2 + 2*128,
                                           rowptr, rowlen, colx, bat, out);
}